// Round 12
// baseline (114.621 us; speedup 1.0000x reference)
//
#include <hip/hip_runtime.h>
#include <hip/hip_bf16.h>
#include <stdint.h>

// costh[B,CK] = (x/||x||_row) @ (W/||W||_col),  x:[B,D] f32, W:[D,CK] f32
// B=512, D=512, CK=5994*3=17982. Output f32.
// ONE persistent kernel, 768 blocks (=3/CU co-residency capacity):
//   Phase A (grid-strided): xnorm units (An tiles) then wtrans units (Wt bf16
//     granule tiles + per-column partial sumsq). After each unit: release
//     threadfence + device-scope atomicAdd on its readiness flag.
//   Phase B (blocks < 564): spin on panel flags (fw[ntile]==8, fx[mtile]==32),
//     acquire threadfence, then R6 GEMM: 128x128, BK=32, 3-buffer rotation,
//     counted vmcnt(4), LDS full-line epilogue, winv folded in.
// No hipLaunchCooperativeKernel (graph capture rejects it - R7). Flags are
// zeroed via captured hipMemsetAsync each call.

#define D_DIM 512
#define BM 128
#define BN 128
#define KITERS 16                  // K-steps of 32
#define TILE_BYTES (64 * BM * 16)  // 131072 B per 128-row tile
#define GRID 768

typedef __bf16 bf16x8 __attribute__((ext_vector_type(8)));
typedef __bf16 bf16x2 __attribute__((ext_vector_type(2)));
typedef float f32x4 __attribute__((ext_vector_type(4)));

__device__ __forceinline__ unsigned pk(float a, float b) {
  bf16x2 t; t[0] = (__bf16)a; t[1] = (__bf16)b;   // v_cvt_pk_bf16_f32 (RNE)
  return __builtin_bit_cast(unsigned, t);
}

__device__ __forceinline__ void load_lds16(const void* g, void* l) {
  __builtin_amdgcn_global_load_lds(
      (__attribute__((address_space(1))) void*)(g),
      (__attribute__((address_space(3))) void*)(l), 16, 0, 0);
}

__global__ __launch_bounds__(256, 3) void fused_kernel(
    const float* __restrict__ x, const float* __restrict__ W,
    unsigned short* __restrict__ An, unsigned short* __restrict__ Wt,
    float* __restrict__ partial, int* __restrict__ flags,
    float* __restrict__ out, int CK, int NT128, int nTiles,
    int nXUnits, int nUnits) {
  __shared__ __attribute__((aligned(16))) unsigned char lds[49152];
  const int t = threadIdx.x;
  const int bid = blockIdx.x;
  int* fw = flags;          // [ntiles] wtrans panel counters (target 8)
  int* fx = flags + 192;    // [mtiles] xnorm counters (target 32)

  // ================= PHASE A: prep (grid-strided units) =================
  for (int u = bid; u < nUnits; u += GRID) {
    if (u < nXUnits) {
      // ---- xnorm unit: 4 rows, one wave per row ----
      const int w = t >> 6, lane = t & 63;
      const int m = u * 4 + w;
      const float* xr = x + (size_t)m * D_DIM + lane * 8;
      float4 a = *(const float4*)(xr);
      float4 c = *(const float4*)(xr + 4);
      float s = a.x * a.x + a.y * a.y + a.z * a.z + a.w * a.w +
                c.x * c.x + c.y * c.y + c.z * c.z + c.w * c.w;
#pragma unroll
      for (int off = 32; off; off >>= 1) s += __shfl_xor(s, off, 64);
      const float inv = 1.f / fmaxf(sqrtf(s), 1e-8f);
      ushort4 o0, o1;
      const unsigned p0 = pk(a.x * inv, a.y * inv), p1 = pk(a.z * inv, a.w * inv);
      const unsigned p2 = pk(c.x * inv, c.y * inv), p3 = pk(c.z * inv, c.w * inv);
      o0.x = (unsigned short)(p0 & 0xffff); o0.y = (unsigned short)(p0 >> 16);
      o0.z = (unsigned short)(p1 & 0xffff); o0.w = (unsigned short)(p1 >> 16);
      o1.x = (unsigned short)(p2 & 0xffff); o1.y = (unsigned short)(p2 >> 16);
      o1.z = (unsigned short)(p3 & 0xffff); o1.w = (unsigned short)(p3 >> 16);
      const int mtile = m >> 7, r = m & 127;
      unsigned short* dst = An + (size_t)mtile * (TILE_BYTES / 2) + (size_t)lane * (BM * 8) + r * 8;
      *(ushort4*)dst = o0;
      *(ushort4*)(dst + 4) = o1;
      __syncthreads();
      if (t == 0) {
        __threadfence();                      // release: WB dirty L2 to coherence point
        atomicAdd(&fx[u >> 5], 1);            // 32 units per mtile
      }
    } else {
      // ---- wtrans unit ----
      float* red = (float*)lds;               // [8][128]
      const int v = u - nXUnits;
      const int ntile = v >> 3, gb = v & 7;
      const int cq = t & 31, dr = t >> 5;
      const int n0 = ntile * BN;
      const int nb = n0 + cq * 4;
      const int g = gb * 8 + dr;              // granule (k/8)
      float ss0 = 0.f, ss1 = 0.f, ss2 = 0.f, ss3 = 0.f;
      unsigned int gr[4][4];                  // [col][pair] packed bf16x2
      if (n0 + BN <= CK) {
#pragma unroll
        for (int i = 0; i < 8; i += 2) {
          float4 v0 = *(const float4*)(W + (size_t)(g * 8 + i) * CK + nb);
          float4 v1 = *(const float4*)(W + (size_t)(g * 8 + i + 1) * CK + nb);
          ss0 += v0.x * v0.x + v1.x * v1.x; ss1 += v0.y * v0.y + v1.y * v1.y;
          ss2 += v0.z * v0.z + v1.z * v1.z; ss3 += v0.w * v0.w + v1.w * v1.w;
          gr[0][i >> 1] = pk(v0.x, v1.x);
          gr[1][i >> 1] = pk(v0.y, v1.y);
          gr[2][i >> 1] = pk(v0.z, v1.z);
          gr[3][i >> 1] = pk(v0.w, v1.w);
        }
      } else {
        float acc_ss[4] = {0.f, 0.f, 0.f, 0.f};
#pragma unroll
        for (int i = 0; i < 8; i += 2) {
#pragma unroll
          for (int e = 0; e < 4; ++e) {
            const int n = nb + e;
            const float f0 = (n < CK) ? W[(size_t)(g * 8 + i) * CK + n] : 0.f;
            const float f1 = (n < CK) ? W[(size_t)(g * 8 + i + 1) * CK + n] : 0.f;
            acc_ss[e] += f0 * f0 + f1 * f1;
            gr[e][i >> 1] = pk(f0, f1);
          }
        }
        ss0 = acc_ss[0]; ss1 = acc_ss[1]; ss2 = acc_ss[2]; ss3 = acc_ss[3];
      }
      unsigned short* dst = Wt + (size_t)ntile * (TILE_BYTES / 2) + (size_t)g * (BM * 8) + (size_t)cq * 32;
#pragma unroll
      for (int e = 0; e < 4; ++e) {
        uint4 o; o.x = gr[e][0]; o.y = gr[e][1]; o.z = gr[e][2]; o.w = gr[e][3];
        *(uint4*)(dst + e * 8) = o;
      }
      *(float4*)(&red[dr * 128 + cq * 4]) = make_float4(ss0, ss1, ss2, ss3);
      __syncthreads();
      if (t < 128) {
        float s = 0.f;
#pragma unroll
        for (int k = 0; k < 8; ++k) s += red[k * 128 + t];
        partial[(size_t)gb * NT128 + n0 + t] = s;
      }
      __syncthreads();                        // red reusable + stores issued
      if (t == 0) {
        __threadfence();                      // release
        atomicAdd(&fw[ntile], 1);
      }
    }
  }

  // ================= PHASE B: GEMM =================
  if (bid >= nTiles) return;
  // bijective XCD swizzle (m204) over nTiles
  const int q = nTiles >> 3, rr = nTiles & 7;
  const int xcd = bid & 7, idx = bid >> 3;
  const int wg = ((xcd < rr) ? xcd * (q + 1) : rr * (q + 1) + (xcd - rr) * q) + idx;
  const int ntile = wg >> 2, mtile = wg & 3;

  // wait for this tile's inputs (device-scope RMW polls), then acquire
  if (t == 0) {
    while (atomicAdd(&fw[ntile], 0) < 8) __builtin_amdgcn_s_sleep(2);
    while (atomicAdd(&fx[mtile], 0) < 32) __builtin_amdgcn_s_sleep(2);
    __threadfence();                          // acquire: invalidate L1/L2
  }
  __syncthreads();

  const int lane = t & 63, w = t >> 6;
  const int wm = w >> 1, wn = w & 1;          // wave -> 64x64 quadrant
  const int lrow = lane & 15;
  const int kg = lane >> 4;                   // k-granule slot 0..3

  const unsigned char* srcA = (const unsigned char*)An + (size_t)mtile * TILE_BYTES;
  const unsigned char* srcB = (const unsigned char*)Wt + (size_t)ntile * TILE_BYTES;
  const int n0 = ntile * BN;
  const bool full = (n0 + BN <= CK);

  f32x4 acc[4][4] = {};

  // one K-step = 8KB A + 8KB B; 2+2 gload_lds per thread (4 vmem ops)
#define STAGE(kt, sel)                                                        \
  {                                                                           \
    const size_t koff = (size_t)(kt) * 8192;                                  \
    unsigned char* bAw = lds + (sel) * 16384;                                 \
    unsigned char* bBw = bAw + 8192;                                          \
    _Pragma("unroll")                                                         \
    for (int c = 0; c < 2; ++c) {                                             \
      const int off = c * 4096 + t * 16;                                      \
      load_lds16(srcA + koff + off, bAw + off);                               \
    }                                                                         \
    _Pragma("unroll")                                                         \
    for (int c = 0; c < 2; ++c) {                                             \
      const int off = c * 4096 + t * 16;                                      \
      load_lds16(srcB + koff + off, bBw + off);                               \
    }                                                                         \
  }

  STAGE(0, 0);

#pragma unroll
  for (int kt = 0; kt < KITERS; ++kt) {
    if (kt + 1 < KITERS) STAGE(kt + 1, (kt + 1) % 3);   // prefetch stays in flight
    __builtin_amdgcn_sched_barrier(0);
    if (kt + 1 < KITERS) {
      asm volatile("s_waitcnt vmcnt(4)" ::: "memory");  // retire STAGE(kt), keep STAGE(kt+1)
    } else {
      asm volatile("s_waitcnt vmcnt(0)" ::: "memory");
    }
    __builtin_amdgcn_s_barrier();
    __builtin_amdgcn_sched_barrier(0);

    const unsigned char* bA = lds + (kt % 3) * 16384;
    const unsigned char* bB = bA + 8192;
    bf16x8 afrag[4], bfrag[4];
#pragma unroll
    for (int i = 0; i < 4; ++i) {
      afrag[i] = *(const bf16x8*)(bA + kg * 2048 + (wm * 64 + i * 16 + lrow) * 16);
      bfrag[i] = *(const bf16x8*)(bB + kg * 2048 + (wn * 64 + i * 16 + lrow) * 16);
    }
#pragma unroll
    for (int i = 0; i < 4; ++i)
#pragma unroll
      for (int j = 0; j < 4; ++j)
        acc[i][j] = __builtin_amdgcn_mfma_f32_16x16x32_bf16(afrag[i], bfrag[j], acc[i][j], 0, 0, 0);
  }
#undef STAGE

  // ---- winv ----
  __syncthreads();                       // all waves done with staging LDS
  float* winv = (float*)lds;             // 128 f32 at base
  if (t < 128) {
    float s = 0.f;
#pragma unroll
    for (int k = 0; k < 8; ++k) s += partial[(size_t)k * NT128 + n0 + t];
    winv[t] = 1.f / fmaxf(sqrtf(s), 1e-8f);
  }
  __syncthreads();
  float wv[4];
#pragma unroll
  for (int j = 0; j < 4; ++j) wv[j] = winv[wn * 64 + j * 16 + lrow];

  // ---- epilogue: full-line writes via wave-private padded LDS ----
  if (full) {
    float* stg = (float*)(lds + 1024) + w * 2176;   // 32*68 floats per wave
    const int l15 = lane & 15, l4 = lane >> 4;
#pragma unroll
    for (int half = 0; half < 2; ++half) {
#pragma unroll
      for (int di = 0; di < 2; ++di)
#pragma unroll
        for (int j = 0; j < 4; ++j)
#pragma unroll
          for (int jj = 0; jj < 4; ++jj)
            stg[(di * 16 + kg * 4 + jj) * 68 + j * 16 + lrow] = acc[half * 2 + di][j][jj] * wv[j];
      // wave-private region: per-wave lgkm ordering suffices, no barrier
#pragma unroll
      for (int s = 0; s < 8; ++s) {
        const int rl = s * 4 + l4;
        float4 v = *(float4*)&stg[rl * 68 + l15 * 4];
        const int row = mtile * BM + wm * 64 + half * 32 + rl;
        *(float4*)&out[(size_t)row * CK + n0 + wn * 64 + l15 * 4] = v;
      }
    }
  } else {
    // tail tile only: scalar stores with bounds check
#pragma unroll
    for (int j = 0; j < 4; ++j) {
      const int col = n0 + wn * 64 + j * 16 + lrow;
      if (col < CK) {
#pragma unroll
        for (int i = 0; i < 4; ++i)
#pragma unroll
          for (int jj = 0; jj < 4; ++jj) {
            const int row = mtile * BM + wm * 64 + i * 16 + kg * 4 + jj;
            out[(size_t)row * CK + col] = acc[i][j][jj] * wv[j];
          }
      }
    }
  }
}

extern "C" void kernel_launch(void* const* d_in, const int* in_sizes, int n_in,
                              void* d_out, int out_size, void* d_ws, size_t ws_size,
                              hipStream_t stream) {
  const float* x = (const float*)d_in[0];
  const float* W = (const float*)d_in[1];
  float* out = (float*)d_out;
  const int Bn = in_sizes[0] / D_DIM;     // 512
  const int CK = in_sizes[1] / D_DIM;     // 17982
  const int ntiles = (CK + BN - 1) / BN;  // 141
  const int mtiles = Bn / BM;             // 4
  const int NT128 = ntiles * BN;          // 18048
  const int nTiles = ntiles * mtiles;     // 564
  const int nXUnits = Bn / 4;             // 128
  const int nUnits = nXUnits + ntiles * 8;// 1256

  unsigned char* ws = (unsigned char*)d_ws;
  int* flags = (int*)ws;                                        // 1 KB (fw@0, fx@192)
  float* partial = (float*)(ws + 1024);                         // 577536 B
  unsigned short* An = (unsigned short*)(ws + 1024 + 8 * (size_t)NT128 * 4);
  unsigned short* Wt = (unsigned short*)(ws + 1024 + 8 * (size_t)NT128 * 4 + (size_t)mtiles * TILE_BYTES);

  hipMemsetAsync(flags, 0, 1024, stream);
  hipLaunchKernelGGL(fused_kernel, dim3(GRID), dim3(256), 0, stream,
                     x, W, An, Wt, partial, flags, out, CK, NT128, nTiles,
                     nXUnits, nUnits);
}

// Round 13
// 92.906 us; speedup vs baseline: 1.2337x; 1.2337x over previous
//
#include <hip/hip_runtime.h>
#include <hip/hip_bf16.h>
#include <stdint.h>

// costh[B,CK] = (x/||x||_row) @ (W/||W||_col),  x:[B,D] f32, W:[D,CK] f32
// B=512, D=512, CK=5994*3=17982. Output f32.
// ONE kernel, grid = nTiles = 564 blocks (all co-resident at 3 blocks/CU):
//   Each block (ntile,mtile):
//     [bid<128]  xnorm unit bid (4 rows of x -> An tiles), fence, fx[mtile]++
//     wtrans units gb={2*mtile, 2*mtile+1} of ITS OWN panel ntile
//       (register transpose + partial column sumsq), fence, fw[ntile]+=2
//     spin (rare: 4 same-XCD siblings) until fw[ntile]==8 && fx[mtile]==32
//     R6 GEMM: 128x128, BK=32, 3-buffer counted-vmcnt(4), LDS full-line epilogue
// Panel Wt is produced & consumed on ONE XCD's L2 (siblings share XCD via the
// swizzle). R12's failure was poll-storm (564 pollers, RMW every 128cyc);
// here polling is ~4 blocks/line with s_sleep(8).

#define D_DIM 512
#define BM 128
#define BN 128
#define KITERS 16                  // K-steps of 32
#define TILE_BYTES (64 * BM * 16)  // 131072 B per 128-row tile

typedef __bf16 bf16x8 __attribute__((ext_vector_type(8)));
typedef __bf16 bf16x2 __attribute__((ext_vector_type(2)));
typedef float f32x4 __attribute__((ext_vector_type(4)));

__device__ __forceinline__ unsigned pk(float a, float b) {
  bf16x2 t; t[0] = (__bf16)a; t[1] = (__bf16)b;   // v_cvt_pk_bf16_f32 (RNE)
  return __builtin_bit_cast(unsigned, t);
}

__device__ __forceinline__ void load_lds16(const void* g, void* l) {
  __builtin_amdgcn_global_load_lds(
      (__attribute__((address_space(1))) void*)(g),
      (__attribute__((address_space(3))) void*)(l), 16, 0, 0);
}

__global__ __launch_bounds__(256, 3) void fused_kernel(
    const float* __restrict__ x, const float* __restrict__ W,
    unsigned short* __restrict__ An, unsigned short* __restrict__ Wt,
    float* __restrict__ partial, int* __restrict__ flags,
    float* __restrict__ out, int CK, int NT128, int nTiles, int nXUnits) {
  __shared__ __attribute__((aligned(16))) unsigned char lds[49152];
  const int t = threadIdx.x;
  const int bid = blockIdx.x;
  int* fw = flags;          // [ntiles] panel counters (target 8)
  int* fx = flags + 192;    // [mtiles] xnorm counters (target 32)

  // bijective XCD swizzle (m204): 4 siblings of a panel share an XCD
  const int q = nTiles >> 3, rr = nTiles & 7;
  const int xcd = bid & 7, idx = bid >> 3;
  const int wg = ((xcd < rr) ? xcd * (q + 1) : rr * (q + 1) + (xcd - rr) * q) + idx;
  const int ntile = wg >> 2, mtile = wg & 3;
  const int n0 = ntile * BN;

  // ================= PHASE A0: xnorm (blocks 0..127) =================
  if (bid < nXUnits) {
    const int w = t >> 6, lane = t & 63;
    const int m = bid * 4 + w;
    const float* xr = x + (size_t)m * D_DIM + lane * 8;
    float4 a = *(const float4*)(xr);
    float4 c = *(const float4*)(xr + 4);
    float s = a.x * a.x + a.y * a.y + a.z * a.z + a.w * a.w +
              c.x * c.x + c.y * c.y + c.z * c.z + c.w * c.w;
#pragma unroll
    for (int off = 32; off; off >>= 1) s += __shfl_xor(s, off, 64);
    const float inv = 1.f / fmaxf(sqrtf(s), 1e-8f);
    ushort4 o0, o1;
    const unsigned p0 = pk(a.x * inv, a.y * inv), p1 = pk(a.z * inv, a.w * inv);
    const unsigned p2 = pk(c.x * inv, c.y * inv), p3 = pk(c.z * inv, c.w * inv);
    o0.x = (unsigned short)(p0 & 0xffff); o0.y = (unsigned short)(p0 >> 16);
    o0.z = (unsigned short)(p1 & 0xffff); o0.w = (unsigned short)(p1 >> 16);
    o1.x = (unsigned short)(p2 & 0xffff); o1.y = (unsigned short)(p2 >> 16);
    o1.z = (unsigned short)(p3 & 0xffff); o1.w = (unsigned short)(p3 >> 16);
    const int mt = m >> 7, r = m & 127;
    unsigned short* dst = An + (size_t)mt * (TILE_BYTES / 2) + (size_t)lane * (BM * 8) + r * 8;
    *(ushort4*)dst = o0;
    *(ushort4*)(dst + 4) = o1;
    __syncthreads();                          // all waves' stores drained (vmcnt0 pre-barrier)
    if (t == 0) {
      __threadfence();                        // release to device scope
      atomicAdd(&fx[bid >> 5], 1);            // 32 units per mtile
    }
  }

  // ================= PHASE A1: wtrans, own panel, gb = 2*mtile + s ==========
  {
    float* red = (float*)lds;                 // [8][128]
    const int cq = t & 31, dr = t >> 5;
    const int nb = n0 + cq * 4;
#pragma unroll
    for (int s = 0; s < 2; ++s) {
      const int gb = mtile * 2 + s;
      const int g = gb * 8 + dr;              // granule (k/8)
      float ss0 = 0.f, ss1 = 0.f, ss2 = 0.f, ss3 = 0.f;
      unsigned int gr[4][4];                  // [col][pair] packed bf16x2
      __syncthreads();                        // red free (prev unit's readers done)
      if (n0 + BN <= CK) {
#pragma unroll
        for (int i = 0; i < 8; i += 2) {
          float4 v0 = *(const float4*)(W + (size_t)(g * 8 + i) * CK + nb);
          float4 v1 = *(const float4*)(W + (size_t)(g * 8 + i + 1) * CK + nb);
          ss0 += v0.x * v0.x + v1.x * v1.x; ss1 += v0.y * v0.y + v1.y * v1.y;
          ss2 += v0.z * v0.z + v1.z * v1.z; ss3 += v0.w * v0.w + v1.w * v1.w;
          gr[0][i >> 1] = pk(v0.x, v1.x);
          gr[1][i >> 1] = pk(v0.y, v1.y);
          gr[2][i >> 1] = pk(v0.z, v1.z);
          gr[3][i >> 1] = pk(v0.w, v1.w);
        }
      } else {
        float acc_ss[4] = {0.f, 0.f, 0.f, 0.f};
#pragma unroll
        for (int i = 0; i < 8; i += 2) {
#pragma unroll
          for (int e = 0; e < 4; ++e) {
            const int n = nb + e;
            const float f0 = (n < CK) ? W[(size_t)(g * 8 + i) * CK + n] : 0.f;
            const float f1 = (n < CK) ? W[(size_t)(g * 8 + i + 1) * CK + n] : 0.f;
            acc_ss[e] += f0 * f0 + f1 * f1;
            gr[e][i >> 1] = pk(f0, f1);
          }
        }
        ss0 = acc_ss[0]; ss1 = acc_ss[1]; ss2 = acc_ss[2]; ss3 = acc_ss[3];
      }
      unsigned short* dst = Wt + (size_t)ntile * (TILE_BYTES / 2) + (size_t)g * (BM * 8) + (size_t)cq * 32;
#pragma unroll
      for (int e = 0; e < 4; ++e) {
        uint4 o; o.x = gr[e][0]; o.y = gr[e][1]; o.z = gr[e][2]; o.w = gr[e][3];
        *(uint4*)(dst + e * 8) = o;
      }
      *(float4*)(&red[dr * 128 + cq * 4]) = make_float4(ss0, ss1, ss2, ss3);
      __syncthreads();
      if (t < 128) {
        float sum = 0.f;
#pragma unroll
        for (int k = 0; k < 8; ++k) sum += red[k * 128 + t];
        partial[(size_t)gb * NT128 + n0 + t] = sum;
      }
    }
    __syncthreads();                          // partial stores drained
    if (t == 0) {
      __threadfence();                        // release
      atomicAdd(&fw[ntile], 2);
    }
  }

  // ================= WAIT: own panel + own mtile (rare, local) ==============
  if (t == 0) {
    while (atomicAdd(&fw[ntile], 0) < 8) __builtin_amdgcn_s_sleep(8);
    while (atomicAdd(&fx[mtile], 0) < 32) __builtin_amdgcn_s_sleep(8);
    __threadfence();                          // acquire
  }
  __syncthreads();

  // ================= PHASE B: GEMM (R6 verbatim) =================
  const int lane = t & 63, w = t >> 6;
  const int wm = w >> 1, wn = w & 1;          // wave -> 64x64 quadrant
  const int lrow = lane & 15;
  const int kg = lane >> 4;                   // k-granule slot 0..3

  const unsigned char* srcA = (const unsigned char*)An + (size_t)mtile * TILE_BYTES;
  const unsigned char* srcB = (const unsigned char*)Wt + (size_t)ntile * TILE_BYTES;
  const bool full = (n0 + BN <= CK);

  f32x4 acc[4][4] = {};

#define STAGE(kt, sel)                                                        \
  {                                                                           \
    const size_t koff = (size_t)(kt) * 8192;                                  \
    unsigned char* bAw = lds + (sel) * 16384;                                 \
    unsigned char* bBw = bAw + 8192;                                          \
    _Pragma("unroll")                                                         \
    for (int c = 0; c < 2; ++c) {                                             \
      const int off = c * 4096 + t * 16;                                      \
      load_lds16(srcA + koff + off, bAw + off);                               \
    }                                                                         \
    _Pragma("unroll")                                                         \
    for (int c = 0; c < 2; ++c) {                                             \
      const int off = c * 4096 + t * 16;                                      \
      load_lds16(srcB + koff + off, bBw + off);                               \
    }                                                                         \
  }

  STAGE(0, 0);

#pragma unroll
  for (int kt = 0; kt < KITERS; ++kt) {
    if (kt + 1 < KITERS) STAGE(kt + 1, (kt + 1) % 3);   // prefetch stays in flight
    __builtin_amdgcn_sched_barrier(0);
    if (kt + 1 < KITERS) {
      asm volatile("s_waitcnt vmcnt(4)" ::: "memory");  // retire STAGE(kt), keep STAGE(kt+1)
    } else {
      asm volatile("s_waitcnt vmcnt(0)" ::: "memory");
    }
    __builtin_amdgcn_s_barrier();
    __builtin_amdgcn_sched_barrier(0);

    const unsigned char* bA = lds + (kt % 3) * 16384;
    const unsigned char* bB = bA + 8192;
    bf16x8 afrag[4], bfrag[4];
#pragma unroll
    for (int i = 0; i < 4; ++i) {
      afrag[i] = *(const bf16x8*)(bA + kg * 2048 + (wm * 64 + i * 16 + lrow) * 16);
      bfrag[i] = *(const bf16x8*)(bB + kg * 2048 + (wn * 64 + i * 16 + lrow) * 16);
    }
#pragma unroll
    for (int i = 0; i < 4; ++i)
#pragma unroll
      for (int j = 0; j < 4; ++j)
        acc[i][j] = __builtin_amdgcn_mfma_f32_16x16x32_bf16(afrag[i], bfrag[j], acc[i][j], 0, 0, 0);
  }
#undef STAGE

  // ---- winv ----
  __syncthreads();                       // all waves done with staging LDS
  float* winv = (float*)lds;             // 128 f32 at base
  if (t < 128) {
    float s = 0.f;
#pragma unroll
    for (int k = 0; k < 8; ++k) s += partial[(size_t)k * NT128 + n0 + t];
    winv[t] = 1.f / fmaxf(sqrtf(s), 1e-8f);
  }
  __syncthreads();
  float wv[4];
#pragma unroll
  for (int j = 0; j < 4; ++j) wv[j] = winv[wn * 64 + j * 16 + lrow];

  // ---- epilogue: full-line writes via wave-private padded LDS ----
  if (full) {
    float* stg = (float*)(lds + 1024) + w * 2176;   // 32*68 floats per wave
    const int l15 = lane & 15, l4 = lane >> 4;
#pragma unroll
    for (int half = 0; half < 2; ++half) {
#pragma unroll
      for (int di = 0; di < 2; ++di)
#pragma unroll
        for (int j = 0; j < 4; ++j)
#pragma unroll
          for (int jj = 0; jj < 4; ++jj)
            stg[(di * 16 + kg * 4 + jj) * 68 + j * 16 + lrow] = acc[half * 2 + di][j][jj] * wv[j];
      // wave-private region: per-wave lgkm ordering suffices, no barrier
#pragma unroll
      for (int s = 0; s < 8; ++s) {
        const int rl = s * 4 + l4;
        float4 v = *(float4*)&stg[rl * 68 + l15 * 4];
        const int row = mtile * BM + wm * 64 + half * 32 + rl;
        *(float4*)&out[(size_t)row * CK + n0 + wn * 64 + l15 * 4] = v;
      }
    }
  } else {
    // tail tile only: scalar stores with bounds check
#pragma unroll
    for (int j = 0; j < 4; ++j) {
      const int col = n0 + wn * 64 + j * 16 + lrow;
      if (col < CK) {
#pragma unroll
        for (int i = 0; i < 4; ++i)
#pragma unroll
          for (int jj = 0; jj < 4; ++jj) {
            const int row = mtile * BM + wm * 64 + i * 16 + kg * 4 + jj;
            out[(size_t)row * CK + col] = acc[i][j][jj] * wv[j];
          }
      }
    }
  }
}

extern "C" void kernel_launch(void* const* d_in, const int* in_sizes, int n_in,
                              void* d_out, int out_size, void* d_ws, size_t ws_size,
                              hipStream_t stream) {
  const float* x = (const float*)d_in[0];
  const float* W = (const float*)d_in[1];
  float* out = (float*)d_out;
  const int Bn = in_sizes[0] / D_DIM;     // 512
  const int CK = in_sizes[1] / D_DIM;     // 17982
  const int ntiles = (CK + BN - 1) / BN;  // 141
  const int mtiles = Bn / BM;             // 4
  const int NT128 = ntiles * BN;          // 18048
  const int nTiles = ntiles * mtiles;     // 564
  const int nXUnits = Bn / 4;             // 128

  unsigned char* ws = (unsigned char*)d_ws;
  int* flags = (int*)ws;                                        // 1 KB (fw@0, fx@192)
  float* partial = (float*)(ws + 1024);                         // 577536 B
  unsigned short* An = (unsigned short*)(ws + 1024 + 8 * (size_t)NT128 * 4);
  unsigned short* Wt = (unsigned short*)(ws + 1024 + 8 * (size_t)NT128 * 4 + (size_t)mtiles * TILE_BYTES);

  hipMemsetAsync(flags, 0, 1024, stream);
  hipLaunchKernelGGL(fused_kernel, dim3(nTiles), dim3(256), 0, stream,
                     x, W, An, Wt, partial, flags, out, CK, NT128, nTiles, nXUnits);
}

// Round 14
// 35.913 us; speedup vs baseline: 3.1916x; 2.5870x over previous
//
#include <hip/hip_runtime.h>
#include <hip/hip_bf16.h>
#include <stdint.h>

// costh[B,CK] = (x/||x||_row) @ (W/||W||_col),  x:[B,D] f32, W:[D,CK] f32
// B=512, D=512, CK=5994*3=17982. Output f32.
// PROVEN OPTIMUM (R6 = 35.88 us). Split two-launch design:
// Kernel 1 (prep): W -> Wt bf16 granule tiles (register transpose, coalesced both
//   sides) + per-column partial sumsq; x -> An normalized tiles (extra blocks).
// Kernel 2 (gemm): 128x128 tile, BK=32, 3-buffer rotation with counted vmcnt(4)
//   (prefetch never drained mid-loop), 3 blocks/CU, LDS-staged full-line epilogue.
// Fusion (cooperative, persistent+flags x2) is structurally dead: consumer reads
// of producer-dirty lines cross XCD L2s (R12/R13: 92-115 us). Split keeps all
// gemm reads clean L3 hits.

#define D_DIM 512
#define BM 128
#define BN 128
#define KITERS 16                  // K-steps of 32
#define TILE_BYTES (64 * BM * 16)  // 131072 B per 128-row tile

typedef __bf16 bf16x8 __attribute__((ext_vector_type(8)));
typedef float f32x4 __attribute__((ext_vector_type(4)));

__device__ __forceinline__ unsigned short f2bf(float f) {
  union { float f; unsigned int u; } v; v.f = f;
  unsigned int u = v.u;
  u += 0x7fffu + ((u >> 16) & 1u);   // RNE
  return (unsigned short)(u >> 16);
}

__device__ __forceinline__ void load_lds16(const void* g, void* l) {
  __builtin_amdgcn_global_load_lds(
      (__attribute__((address_space(1))) void*)(g),
      (__attribute__((address_space(3))) void*)(l), 16, 0, 0);
}

// ---------------- kernel 1: prep (wtrans blocks + xnorm blocks) ----------------
__global__ void prep_kernel(const float* __restrict__ x, const float* __restrict__ W,
                            unsigned short* __restrict__ An, unsigned short* __restrict__ Wt,
                            float* __restrict__ partial, int CK, int NT128, int nWtBlocks) {
  const int b = blockIdx.x;
  const int t = threadIdx.x;
  if (b < nWtBlocks) {
    __shared__ float red[8 * 128];
    const int ntile = b >> 3, gb = b & 7;
    const int cq = t & 31, dr = t >> 5;
    const int n0 = ntile * BN;
    const int nb = n0 + cq * 4;
    const int g = gb * 8 + dr;               // granule (k/8)
    float ss0 = 0.f, ss1 = 0.f, ss2 = 0.f, ss3 = 0.f;
    unsigned int gr[4][4];                   // [col][pair] packed bf16x2
    if (n0 + BN <= CK) {
#pragma unroll
      for (int i = 0; i < 8; i += 2) {
        float4 v0 = *(const float4*)(W + (size_t)(g * 8 + i) * CK + nb);
        float4 v1 = *(const float4*)(W + (size_t)(g * 8 + i + 1) * CK + nb);
        ss0 += v0.x * v0.x + v1.x * v1.x; ss1 += v0.y * v0.y + v1.y * v1.y;
        ss2 += v0.z * v0.z + v1.z * v1.z; ss3 += v0.w * v0.w + v1.w * v1.w;
        gr[0][i >> 1] = (unsigned int)f2bf(v0.x) | ((unsigned int)f2bf(v1.x) << 16);
        gr[1][i >> 1] = (unsigned int)f2bf(v0.y) | ((unsigned int)f2bf(v1.y) << 16);
        gr[2][i >> 1] = (unsigned int)f2bf(v0.z) | ((unsigned int)f2bf(v1.z) << 16);
        gr[3][i >> 1] = (unsigned int)f2bf(v0.w) | ((unsigned int)f2bf(v1.w) << 16);
      }
    } else {
      float acc_ss[4] = {0.f, 0.f, 0.f, 0.f};
#pragma unroll
      for (int i = 0; i < 8; i += 2) {
#pragma unroll
        for (int e = 0; e < 4; ++e) {
          const int n = nb + e;
          const float f0 = (n < CK) ? W[(size_t)(g * 8 + i) * CK + n] : 0.f;
          const float f1 = (n < CK) ? W[(size_t)(g * 8 + i + 1) * CK + n] : 0.f;
          acc_ss[e] += f0 * f0 + f1 * f1;
          gr[e][i >> 1] = (unsigned int)f2bf(f0) | ((unsigned int)f2bf(f1) << 16);
        }
      }
      ss0 = acc_ss[0]; ss1 = acc_ss[1]; ss2 = acc_ss[2]; ss3 = acc_ss[3];
    }
    unsigned short* dst = Wt + (size_t)ntile * (TILE_BYTES / 2) + (size_t)g * (BM * 8) + (size_t)cq * 32;
#pragma unroll
    for (int e = 0; e < 4; ++e) {
      uint4 o; o.x = gr[e][0]; o.y = gr[e][1]; o.z = gr[e][2]; o.w = gr[e][3];
      *(uint4*)(dst + e * 8) = o;
    }
    *(float4*)(&red[dr * 128 + cq * 4]) = make_float4(ss0, ss1, ss2, ss3);
    __syncthreads();
    if (t < 128) {
      float s = 0.f;
#pragma unroll
      for (int k = 0; k < 8; ++k) s += red[k * 128 + t];
      partial[(size_t)gb * NT128 + n0 + t] = s;
    }
  } else {
    // xnorm: 4 rows per block, one wave per row
    const int w = t >> 6, lane = t & 63;
    const int m = (b - nWtBlocks) * 4 + w;
    const float* xr = x + (size_t)m * D_DIM + lane * 8;
    float4 a = *(const float4*)(xr);
    float4 c = *(const float4*)(xr + 4);
    float s = a.x * a.x + a.y * a.y + a.z * a.z + a.w * a.w +
              c.x * c.x + c.y * c.y + c.z * c.z + c.w * c.w;
#pragma unroll
    for (int off = 32; off; off >>= 1) s += __shfl_xor(s, off, 64);
    const float inv = 1.f / fmaxf(sqrtf(s), 1e-8f);
    ushort4 o0, o1;
    o0.x = f2bf(a.x * inv); o0.y = f2bf(a.y * inv); o0.z = f2bf(a.z * inv); o0.w = f2bf(a.w * inv);
    o1.x = f2bf(c.x * inv); o1.y = f2bf(c.y * inv); o1.z = f2bf(c.z * inv); o1.w = f2bf(c.w * inv);
    const int mtile = m >> 7, r = m & 127;
    unsigned short* dst = An + (size_t)mtile * (TILE_BYTES / 2) + (size_t)lane * (BM * 8) + r * 8;
    *(ushort4*)dst = o0;
    *(ushort4*)(dst + 4) = o1;
  }
}

// ---------------- kernel 2: GEMM, BK=32, 3-buffer counted-vmcnt pipeline ----------------
// LDS: 3 staging buffers of 16KB (A 8K + B 8K); epilogue reuses [1024, 35840).
__global__ __launch_bounds__(256, 3) void gemm_kernel(const unsigned short* __restrict__ An,
                                                      const unsigned short* __restrict__ Wt,
                                                      const float* __restrict__ partial,
                                                      float* __restrict__ out, int CK, int NT128) {
  __shared__ __attribute__((aligned(16))) unsigned char lds[49152];
  // bijective XCD swizzle (m204)
  const int total = gridDim.x;
  const int q = total >> 3, rr = total & 7;
  const int lin = blockIdx.x;
  const int xcd = lin & 7, idx = lin >> 3;
  const int wg = ((xcd < rr) ? xcd * (q + 1) : rr * (q + 1) + (xcd - rr) * q) + idx;
  const int ntile = wg >> 2, mtile = wg & 3;

  const int t = threadIdx.x;
  const int lane = t & 63, w = t >> 6;
  const int wm = w >> 1, wn = w & 1;          // wave -> 64x64 quadrant
  const int lrow = lane & 15;
  const int kg = lane >> 4;                   // k-granule slot 0..3

  const unsigned char* srcA = (const unsigned char*)An + (size_t)mtile * TILE_BYTES;
  const unsigned char* srcB = (const unsigned char*)Wt + (size_t)ntile * TILE_BYTES;
  const int n0 = ntile * BN;
  const bool full = (n0 + BN <= CK);

  f32x4 acc[4][4] = {};

  // one K-step = 8KB A + 8KB B; 2+2 gload_lds per thread
#define STAGE(kt, sel)                                                        \
  {                                                                           \
    const size_t koff = (size_t)(kt) * 8192;                                  \
    unsigned char* bAw = lds + (sel) * 16384;                                 \
    unsigned char* bBw = bAw + 8192;                                          \
    _Pragma("unroll")                                                         \
    for (int c = 0; c < 2; ++c) {                                             \
      const int off = c * 4096 + t * 16;                                      \
      load_lds16(srcA + koff + off, bAw + off);                               \
    }                                                                         \
    _Pragma("unroll")                                                         \
    for (int c = 0; c < 2; ++c) {                                             \
      const int off = c * 4096 + t * 16;                                      \
      load_lds16(srcB + koff + off, bBw + off);                               \
    }                                                                         \
  }

  STAGE(0, 0);

#pragma unroll
  for (int kt = 0; kt < KITERS; ++kt) {
    if (kt + 1 < KITERS) STAGE(kt + 1, (kt + 1) % 3);   // prefetch stays in flight
    __builtin_amdgcn_sched_barrier(0);
    if (kt + 1 < KITERS) {
      asm volatile("s_waitcnt vmcnt(4)" ::: "memory");  // retire STAGE(kt), keep STAGE(kt+1)
    } else {
      asm volatile("s_waitcnt vmcnt(0)" ::: "memory");
    }
    __builtin_amdgcn_s_barrier();
    __builtin_amdgcn_sched_barrier(0);

    const unsigned char* bA = lds + (kt % 3) * 16384;
    const unsigned char* bB = bA + 8192;
    bf16x8 afrag[4], bfrag[4];
#pragma unroll
    for (int i = 0; i < 4; ++i) {
      afrag[i] = *(const bf16x8*)(bA + kg * 2048 + (wm * 64 + i * 16 + lrow) * 16);
      bfrag[i] = *(const bf16x8*)(bB + kg * 2048 + (wn * 64 + i * 16 + lrow) * 16);
    }
#pragma unroll
    for (int i = 0; i < 4; ++i)
#pragma unroll
      for (int j = 0; j < 4; ++j)
        acc[i][j] = __builtin_amdgcn_mfma_f32_16x16x32_bf16(afrag[i], bfrag[j], acc[i][j], 0, 0, 0);
  }

  // ---- winv ----
  __syncthreads();                       // all waves done with staging LDS
  float* winv = (float*)lds;             // 128 f32 at base
  if (t < 128) {
    float s = 0.f;
#pragma unroll
    for (int k = 0; k < 8; ++k) s += partial[(size_t)k * NT128 + n0 + t];
    winv[t] = 1.f / fmaxf(sqrtf(s), 1e-8f);
  }
  __syncthreads();
  float wv[4];
#pragma unroll
  for (int j = 0; j < 4; ++j) wv[j] = winv[wn * 64 + j * 16 + lrow];

  // ---- epilogue ----
  // C frag layout: col=lane&15, row=(lane>>4)*4+reg. Stage per-wave 32x64 f32
  // halves in wave-private padded LDS (stride 68 f32 = 272B, 16B-aligned rows),
  // then float4 stores: 256B contiguous per row -> full-line HBM writes.
  if (full) {
    float* stg = (float*)(lds + 1024) + w * 2176;   // 32*68 floats per wave
    const int l15 = lane & 15, l4 = lane >> 4;
#pragma unroll
    for (int half = 0; half < 2; ++half) {
#pragma unroll
      for (int di = 0; di < 2; ++di)
#pragma unroll
        for (int j = 0; j < 4; ++j)
#pragma unroll
          for (int jj = 0; jj < 4; ++jj)
            stg[(di * 16 + kg * 4 + jj) * 68 + j * 16 + lrow] = acc[half * 2 + di][j][jj] * wv[j];
      // wave-private region: per-wave lgkm ordering suffices, no barrier
#pragma unroll
      for (int s = 0; s < 8; ++s) {
        const int rl = s * 4 + l4;
        float4 v = *(float4*)&stg[rl * 68 + l15 * 4];
        const int row = mtile * BM + wm * 64 + half * 32 + rl;
        *(float4*)&out[(size_t)row * CK + n0 + wn * 64 + l15 * 4] = v;
      }
    }
  } else {
    // tail ntile only (1 of 141): scalar stores with bounds check
#pragma unroll
    for (int j = 0; j < 4; ++j) {
      const int col = n0 + wn * 64 + j * 16 + lrow;
      if (col < CK) {
#pragma unroll
        for (int i = 0; i < 4; ++i)
#pragma unroll
          for (int jj = 0; jj < 4; ++jj) {
            const int row = mtile * BM + wm * 64 + i * 16 + kg * 4 + jj;
            out[(size_t)row * CK + col] = acc[i][j][jj] * wv[j];
          }
      }
    }
  }
#undef STAGE
}

extern "C" void kernel_launch(void* const* d_in, const int* in_sizes, int n_in,
                              void* d_out, int out_size, void* d_ws, size_t ws_size,
                              hipStream_t stream) {
  const float* x = (const float*)d_in[0];
  const float* W = (const float*)d_in[1];
  float* out = (float*)d_out;
  const int Bn = in_sizes[0] / D_DIM;     // 512
  const int CK = in_sizes[1] / D_DIM;     // 17982
  const int ntiles = (CK + BN - 1) / BN;  // 141
  const int mtiles = Bn / BM;             // 4
  const int NT128 = ntiles * BN;          // 18048

  unsigned char* ws = (unsigned char*)d_ws;
  float* partial = (float*)ws;                                  // 8*NT128*4 = 577536 B
  unsigned short* An = (unsigned short*)(ws + 8 * (size_t)NT128 * 4);
  unsigned short* Wt = (unsigned short*)(ws + 8 * (size_t)NT128 * 4 + (size_t)mtiles * TILE_BYTES);

  const int nWtBlocks = ntiles * 8;
  const int nXBlocks = Bn / 4;            // 128
  hipLaunchKernelGGL(prep_kernel, dim3(nWtBlocks + nXBlocks), dim3(256), 0, stream,
                     x, W, An, Wt, partial, CK, NT128, nWtBlocks);
  hipLaunchKernelGGL(gemm_kernel, dim3(ntiles * mtiles), dim3(256), 0, stream,
                     An, Wt, partial, out, CK, NT128);
}